// Round 7
// baseline (215.160 us; speedup 1.0000x reference)
//
#include <hip/hip_runtime.h>
#include <math.h>

#define D 2048
#define EPS_COS 1e-8f
#define EPS_DEN 1e-6f
#define INV_TEMP 10.0f
#define TPB 512
#define WPB 8                   // waves per block
#define RPW 8                   // rows per wave (double-buffer pipelined)
#define NBLK 256                // 256*8*8 = 16384 rows; 1 block/CU
#define NSLOT 64                // spread denominator slots (contention-free)

// pos_pair: reference declares int64 but JAX x64-off makes it int32.
// Hedge: accept int32 reading iff plausible (in range, i != j), else int64.
__device__ __forceinline__ void get_ij(const int* __restrict__ p, int n,
                                       int& i, int& j) {
    int i32 = p[0], j32 = p[1];
    if (i32 >= 0 && i32 < n && j32 >= 0 && j32 < n && i32 != j32) {
        i = i32; j = j32; return;
    }
    const long long* p64 = (const long long*)p;
    i = (int)p64[0]; j = (int)p64[1];
}

// Single fused kernel, 256 blocks (1/CU). Streaming core identical to R5
// (xi in regs, double-buffered row prefetch, 8 rows/wave). Tail: per-block
// LDS reduce -> spread-slot atomicAdd (64 slots, no contention) -> ordered
// done-counter (only 256 same-address atomics ~5us vs R4's 2048 ~41us)
// -> last block coherently reads slots and finishes the loss. No fences.
__global__ __launch_bounds__(TPB)
void fused_kernel(const float* __restrict__ x, const int* __restrict__ pos,
                  float* __restrict__ out, float* __restrict__ accf,
                  unsigned* __restrict__ accu, int n) {
    int i, j;
    get_ij(pos, n, i, j);
    const int lane  = threadIdx.x & 63;
    const int wave  = threadIdx.x >> 6;
    const int gwave = blockIdx.x * WPB + wave;
    const int row0  = gwave * RPW;

    const float4* __restrict__ xi = (const float4*)(x + (size_t)i * D);

    // issue row0 + xi loads together (16 float4 in flight before any math)
    float4 b[8], a[2][8];
    const float4* __restrict__ p0 = (const float4*)(x + (size_t)row0 * D);
#pragma unroll
    for (int w = 0; w < 8; ++w) a[0][w] = p0[lane + w * 64];
#pragma unroll
    for (int w = 0; w < 8; ++w) b[w] = xi[lane + w * 64];

    float sqi = 0.f;
#pragma unroll
    for (int w = 0; w < 8; ++w)
        sqi = fmaf(b[w].x, b[w].x, fmaf(b[w].y, b[w].y,
              fmaf(b[w].z, b[w].z, fmaf(b[w].w, b[w].w, sqi))));
#pragma unroll
    for (int off = 32; off; off >>= 1) sqi += __shfl_down(sqi, off);
    const float ni = fmaxf(sqrtf(sqi), EPS_COS);   // valid in lane 0

    float den_local = 0.f, ej = 0.f;               // lane-0 accumulators

#pragma unroll
    for (int r = 0; r < RPW; ++r) {
        if (r + 1 < RPW) {                         // prefetch next row
            const float4* __restrict__ pn =
                (const float4*)(x + (size_t)(row0 + r + 1) * D);
#pragma unroll
            for (int w = 0; w < 8; ++w) a[(r + 1) & 1][w] = pn[lane + w * 64];
        }
        float dot = 0.f, sq = 0.f;
#pragma unroll
        for (int w = 0; w < 8; ++w) {
            float4 c = a[r & 1][w];
            dot = fmaf(c.x, b[w].x, fmaf(c.y, b[w].y,
                  fmaf(c.z, b[w].z, fmaf(c.w, b[w].w, dot))));
            sq  = fmaf(c.x, c.x, fmaf(c.y, c.y,
                  fmaf(c.z, c.z, fmaf(c.w, c.w, sq))));
        }
#pragma unroll
        for (int off = 32; off; off >>= 1) {
            dot += __shfl_down(dot, off);
            sq  += __shfl_down(sq,  off);
        }
        if (lane == 0) {
            const int row = row0 + r;
            float e = expf(INV_TEMP * dot / (fmaxf(sqrtf(sq), EPS_COS) * ni));
            if (row != i) den_local += e;   // den includes k==j, excludes k==i
            if (row == j) ej = e;
        }
    }

    __shared__ float s_den[WPB], s_ej[WPB];
    if (lane == 0) {
        s_den[wave] = den_local;
        s_ej[wave]  = ej;
    }
    __syncthreads();

    if (threadIdx.x == 0) {
        float bden = 0.f, bej = 0.f;
#pragma unroll
        for (int w = 0; w < WPB; ++w) { bden += s_den[w]; bej += s_ej[w]; }
        float r1 = atomicAdd(&accf[blockIdx.x & (NSLOT - 1)], bden);
        float r2 = (bej != 0.f) ? atomicAdd(&accf[NSLOT], bej) : 0.f;
        // order slot-adds before the done signal: consume returned values
        // (data dep) + explicit drain of outstanding VMEM.
        unsigned inc = 1u
            + ((__float_as_uint(r1) == 0x7F800001u) ? 1u : 0u)   // never true
            + ((__float_as_uint(r2) == 0x7F800001u) ? 1u : 0u);  // never true
        asm volatile("s_waitcnt vmcnt(0)" ::: "memory");
        unsigned old = atomicAdd(accu, inc);
        if (old == (unsigned)(NBLK - 1)) {      // last block finishes the loss
            float den = 0.f;
#pragma unroll
            for (int s = 0; s < NSLOT; ++s) den += atomicAdd(&accf[s], 0.f);
            float nom = atomicAdd(&accf[NSLOT], 0.f);
            out[0] = -logf(nom / (den + EPS_DEN));
        }
    }
}

extern "C" void kernel_launch(void* const* d_in, const int* in_sizes, int n_in,
                              void* d_out, int out_size, void* d_ws, size_t ws_size,
                              hipStream_t stream) {
    const float* x    = (const float*)d_in[0];
    const int*   pos  = (const int*)d_in[1];
    float*       out  = (float*)d_out;
    float*       accf = (float*)d_ws;                    // [0..63] den, [64] nom
    unsigned*    accu = (unsigned*)d_ws + NSLOT + 1;     // done counter

    const int n = in_sizes[0] / D;                       // 16384

    hipMemsetAsync(d_ws, 0, (NSLOT + 2) * sizeof(float), stream);
    fused_kernel<<<NBLK, TPB, 0, stream>>>(x, pos, out, accf, accu, n);
}

// Round 8
// 188.538 us; speedup vs baseline: 1.1412x; 1.1412x over previous
//
#include <hip/hip_runtime.h>
#include <math.h>

#define D 2048
#define EPS_COS 1e-8f
#define EPS_DEN 1e-6f
#define INV_TEMP 10.0f
#define TPB 256
#define WPB 4                   // waves per block
#define RPW 4                   // rows per wave
#define NBLK 1024               // 1024*4*4 = 16384 rows

#if defined(__has_builtin)
#if __has_builtin(__builtin_amdgcn_sched_barrier)
#define SCHED_PIN() __builtin_amdgcn_sched_barrier(0)
#endif
#endif
#ifndef SCHED_PIN
#define SCHED_PIN()
#endif

// pos_pair: reference declares int64 but JAX x64-off makes it int32.
// Hedge: accept int32 reading iff plausible (in range, i != j), else int64.
__device__ __forceinline__ void get_ij(const int* __restrict__ p, int n,
                                       int& i, int& j) {
    int i32 = p[0], j32 = p[1];
    if (i32 >= 0 && i32 < n && j32 >= 0 && j32 < n && i32 != j32) {
        i = i32; j = j32; return;
    }
    const long long* p64 = (const long long*)p;
    i = (int)p64[0]; j = (int)p64[1];
}

// Kernel 1: wave-per-4-rows with a REAL depth-2 prefetch pipeline.
// R7's profile showed VGPR=56 for a kernel declaring 96 regs of buffers:
// the compiler sank the prefetch loads to their uses, exposing full memory
// latency per row. sched_barrier(0) pins issue order so rows r+1,r+2 stay
// in flight while row r reduces. Load order xi->A0->A1 keeps the xi-norm
// wait at vmcnt(16). Dot/sq chains split 4-way (dep depth 8, not 32).
__global__ __launch_bounds__(TPB)
void e_kernel(const float* __restrict__ x, const int* __restrict__ pos,
              float* __restrict__ part, float* __restrict__ nom, int n) {
    int i, j;
    get_ij(pos, n, i, j);
    const int lane  = threadIdx.x & 63;
    const int wave  = threadIdx.x >> 6;
    const int gwave = blockIdx.x * WPB + wave;
    const int row0  = gwave * RPW;

    const float4* __restrict__ xi = (const float4*)(x + (size_t)i * D);

    float4 b[8], A[3][8];
#pragma unroll
    for (int w = 0; w < 8; ++w) b[w] = xi[lane + w * 64];          // first
    {
        const float4* __restrict__ p0 = (const float4*)(x + (size_t)row0 * D);
        const float4* __restrict__ p1 = (const float4*)(x + (size_t)(row0 + 1) * D);
#pragma unroll
        for (int w = 0; w < 8; ++w) A[0][w] = p0[lane + w * 64];
#pragma unroll
        for (int w = 0; w < 8; ++w) A[1][w] = p1[lane + w * 64];
    }
    SCHED_PIN();   // b, A0, A1 issued; nothing below may move above

    // xi norm while row loads fly (waits vmcnt(16): only b needed)
    float q0 = 0.f, q1 = 0.f, q2 = 0.f, q3 = 0.f;
#pragma unroll
    for (int w = 0; w < 8; ++w) {
        float4 c = b[w];
        float p = fmaf(c.x, c.x, fmaf(c.y, c.y, fmaf(c.z, c.z, c.w * c.w)));
        if ((w & 3) == 0) q0 += p; else if ((w & 3) == 1) q1 += p;
        else if ((w & 3) == 2) q2 += p; else q3 += p;
    }
    float sqi = (q0 + q1) + (q2 + q3);
#pragma unroll
    for (int off = 32; off; off >>= 1) sqi += __shfl_down(sqi, off);
    const float ni = fmaxf(sqrtf(sqi), EPS_COS);   // valid in lane 0

    float den_local = 0.f, ej = 0.f;               // lane-0 accumulators

#pragma unroll
    for (int r = 0; r < RPW; ++r) {
        if (r + 2 < RPW) {                         // prefetch row r+2
            const float4* __restrict__ pn =
                (const float4*)(x + (size_t)(row0 + r + 2) * D);
#pragma unroll
            for (int w = 0; w < 8; ++w) A[(r + 2) % 3][w] = pn[lane + w * 64];
        }
        SCHED_PIN();   // prefetch issued BEFORE row r consumption

        float d0 = 0.f, d1 = 0.f, d2 = 0.f, d3 = 0.f;
        float s0 = 0.f, s1 = 0.f, s2 = 0.f, s3 = 0.f;
#pragma unroll
        for (int w = 0; w < 8; ++w) {
            float4 c = A[r % 3][w];
            float4 e = b[w];
            float dp = fmaf(c.x, e.x, fmaf(c.y, e.y, fmaf(c.z, e.z, c.w * e.w)));
            float sp = fmaf(c.x, c.x, fmaf(c.y, c.y, fmaf(c.z, c.z, c.w * c.w)));
            if ((w & 3) == 0) { d0 += dp; s0 += sp; }
            else if ((w & 3) == 1) { d1 += dp; s1 += sp; }
            else if ((w & 3) == 2) { d2 += dp; s2 += sp; }
            else { d3 += dp; s3 += sp; }
        }
        float dot = (d0 + d1) + (d2 + d3);
        float sq  = (s0 + s1) + (s2 + s3);
#pragma unroll
        for (int off = 32; off; off >>= 1) {
            dot += __shfl_down(dot, off);
            sq  += __shfl_down(sq,  off);
        }
        if (lane == 0) {
            const int row = row0 + r;
            float e = expf(INV_TEMP * dot / (fmaxf(sqrtf(sq), EPS_COS) * ni));
            if (row != i) den_local += e;   // den includes k==j, excludes k==i
            if (row == j) ej = e;
        }
    }

    __shared__ float s_den[WPB];
    if (lane == 0) {
        s_den[wave] = den_local;
        if (ej != 0.f) *nom = ej;           // exactly one wave owns row j
    }
    __syncthreads();
    if (threadIdx.x == 0)
        part[blockIdx.x] = (s_den[0] + s_den[1]) + (s_den[2] + s_den[3]);
}

// Kernel 2: one 256-thread block sums 1024 partials (4 KB) + finishes loss.
__global__ __launch_bounds__(256)
void loss_kernel(const float* __restrict__ part, const float* __restrict__ nom,
                 float* __restrict__ out, int nblk) {
    const int t = threadIdx.x;
    float s = 0.f;
    if (t < nblk / 4) {
        float4 v = ((const float4*)part)[t];
        s = (v.x + v.y) + (v.z + v.w);
    }
#pragma unroll
    for (int off = 32; off; off >>= 1) s += __shfl_down(s, off);

    __shared__ float ls[4];
    if ((t & 63) == 0) ls[t >> 6] = s;
    __syncthreads();

    if (t == 0) {
        float den = (ls[0] + ls[1]) + (ls[2] + ls[3]);
        out[0] = -logf(nom[0] / (den + EPS_DEN));
    }
}

extern "C" void kernel_launch(void* const* d_in, const int* in_sizes, int n_in,
                              void* d_out, int out_size, void* d_ws, size_t ws_size,
                              hipStream_t stream) {
    const float* x    = (const float*)d_in[0];
    const int*   pos  = (const int*)d_in[1];
    float*       out  = (float*)d_out;

    const int n = in_sizes[0] / D;                 // 16384

    float* part = (float*)d_ws;                    // [0..NBLK) block partials
    float* nom  = (float*)d_ws + NBLK;             // e_j slot

    e_kernel<<<NBLK, TPB, 0, stream>>>(x, pos, part, nom, n);
    loss_kernel<<<1, 256, 0, stream>>>(part, nom, out, NBLK);
}